// Round 9
// baseline (295.521 us; speedup 1.0000x reference)
//
#include <hip/hip_runtime.h>
#include <hip/hip_fp16.h>

// ---------------------------------------------------------------------------
// 3-layer GCN (PyG GCNConv, add_self_loops=False) on MI355X.
//   deg[dst]++ (XCD-partitioned) -> rowptr=exscan(deg), dinv=rsqrt(deg),
//   fillc=rowptr -> fill CSR (XCD-partitioned; csr_src only, 4B/edge)
//   per layer: Hh = fp16( dinv[row] * (X@W) )        [gemm epilogue]
//              G[i] = BN/ReLU( dinv[i]*sum_p Hh[csr_src[p],:] + bias )
// Round-7: partitioned scatter cut fill 70->49us, WRITE 69->42MB — but slices
// (~550KB) should be L2-resident. Residual amp = streaming dst/src reads
// (8MB/XCD) evicting the scatter lines mid-kernel. This round: nontemporal
// loads (ext_vector_type — HIP int4 is rejected by the builtin) for dst/src
// in count_deg+fill so the scatter slices own the L2.
// ---------------------------------------------------------------------------

struct half4 { __half2 a, b; };
typedef int iv4 __attribute__((ext_vector_type(4)));

constexpr int SCAN_T = 256;
constexpr int SCAN_E = 8;
constexpr int SCAN_B = SCAN_T * SCAN_E; // 2048 elems per scan block
constexpr int NPART = 8;
constexpr int ECHUNK = 2048;            // edges per partition-block

__global__ __launch_bounds__(256) void k_count_deg(const int* __restrict__ dst,
                                                   int* __restrict__ deg,
                                                   int E, int PS) {
  const int p = blockIdx.x & 7;
  const int lo = p * PS, hi = lo + PS;
  const int base = (blockIdx.x >> 3) * ECHUNK + threadIdx.x * 4;
#pragma unroll
  for (int h = 0; h < 2; ++h) {
    int e = base + h * 1024;
    if (e + 3 < E) {
      iv4 d4 = __builtin_nontemporal_load(
          reinterpret_cast<const iv4*>(&dst[e]));
      if (d4.x >= lo && d4.x < hi) atomicAdd(&deg[d4.x], 1);
      if (d4.y >= lo && d4.y < hi) atomicAdd(&deg[d4.y], 1);
      if (d4.z >= lo && d4.z < hi) atomicAdd(&deg[d4.z], 1);
      if (d4.w >= lo && d4.w < hi) atomicAdd(&deg[d4.w], 1);
    } else {
      for (int j = 0; j < 4; ++j) {
        int ee = e + j;
        if (ee < E) {
          int d = dst[ee];
          if (d >= lo && d < hi) atomicAdd(&deg[d], 1);
        }
      }
    }
  }
}

__global__ __launch_bounds__(SCAN_T) void k_scan1(const int* __restrict__ deg,
                                                  int* __restrict__ pre,
                                                  int* __restrict__ bsum, int N) {
  __shared__ int ls[SCAN_T];
  int t = threadIdx.x;
  int base = blockIdx.x * SCAN_B + t * SCAN_E;
  int v[SCAN_E];
  int s = 0;
#pragma unroll
  for (int j = 0; j < SCAN_E; ++j) {
    int idx = base + j;
    v[j] = (idx < N) ? deg[idx] : 0;
    s += v[j];
  }
  ls[t] = s;
  __syncthreads();
  for (int off = 1; off < SCAN_T; off <<= 1) {
    int x = 0;
    if (t >= off) x = ls[t - off];
    __syncthreads();
    ls[t] += x;
    __syncthreads();
  }
  if (t == SCAN_T - 1) bsum[blockIdx.x] = ls[t];
  int run = (t > 0) ? ls[t - 1] : 0;
#pragma unroll
  for (int j = 0; j < SCAN_E; ++j) {
    int idx = base + j;
    if (idx < N) pre[idx] = run;
    run += v[j];
  }
}

__global__ __launch_bounds__(SCAN_T) void k_scan2(int* __restrict__ bsum, int nb) {
  __shared__ int ls[SCAN_T];
  int t = threadIdx.x;
  ls[t] = (t < nb) ? bsum[t] : 0;
  __syncthreads();
  for (int off = 1; off < SCAN_T; off <<= 1) {
    int x = 0;
    if (t >= off) x = ls[t - off];
    __syncthreads();
    ls[t] += x;
    __syncthreads();
  }
  if (t < nb) bsum[t] = (t > 0) ? ls[t - 1] : 0;
}

// rowptr += block offset; fillc = rowptr (absolute slot counters); dinv.
__global__ __launch_bounds__(256) void k_scan3(int* __restrict__ rowptr,
                                               int* __restrict__ fillc,
                                               const int* __restrict__ bsum,
                                               const int* __restrict__ deg,
                                               float* __restrict__ dinv,
                                               int N, int E) {
  int i = blockIdx.x * 256 + threadIdx.x;
  if (i < N) {
    int r = rowptr[i] + bsum[i / SCAN_B];
    rowptr[i] = r;
    fillc[i] = r;
    int d = deg[i];
    dinv[i] = (d > 0) ? rsqrtf((float)d) : 0.f;
  }
  if (i == 0) rowptr[N] = E;
}

__global__ __launch_bounds__(256) void k_fill(const int* __restrict__ src,
                                              const int* __restrict__ dst,
                                              int* __restrict__ fillc,
                                              int* __restrict__ csr_src,
                                              int E, int PS) {
  const int p = blockIdx.x & 7;
  const int lo = p * PS, hi = lo + PS;
  const int base = (blockIdx.x >> 3) * ECHUNK + threadIdx.x * 4;
#pragma unroll
  for (int h = 0; h < 2; ++h) {
    int e = base + h * 1024;
    if (e + 3 < E) {
      iv4 d4 = __builtin_nontemporal_load(
          reinterpret_cast<const iv4*>(&dst[e]));
      iv4 s4 = __builtin_nontemporal_load(
          reinterpret_cast<const iv4*>(&src[e]));
      if (d4.x >= lo && d4.x < hi) csr_src[atomicAdd(&fillc[d4.x], 1)] = s4.x;
      if (d4.y >= lo && d4.y < hi) csr_src[atomicAdd(&fillc[d4.y], 1)] = s4.y;
      if (d4.z >= lo && d4.z < hi) csr_src[atomicAdd(&fillc[d4.z], 1)] = s4.z;
      if (d4.w >= lo && d4.w < hi) csr_src[atomicAdd(&fillc[d4.w], 1)] = s4.w;
    } else {
      for (int j = 0; j < 4; ++j) {
        int ee = e + j;
        if (ee < E) {
          int d = dst[ee];
          if (d >= lo && d < hi) csr_src[atomicAdd(&fillc[d], 1)] = src[ee];
        }
      }
    }
  }
}

// Hh[row, :] = fp16( dinv[row] * (X[N,K] @ W[K,F]) ).  Thread = 4 rows x 4
// cols (16 fp32 acc).  W and X staged in K-chunks of KC<=64 (LDS ~33KB for
// K=128 -> 4 blocks/CU).
template <int K, int F>
__global__ __launch_bounds__(256) void k_gemm(const float* __restrict__ X,
                                              const float* __restrict__ W,
                                              const float* __restrict__ dinv,
                                              __half* __restrict__ Hh, int N) {
  constexpr int CG = F / 4;            // 16 (F=64) or 10 (F=40)
  constexpr int RG = 256 / CG;         // 16 or 25
  constexpr int ROWS = RG * 4;         // 64 or 100
  constexpr int KC = (K > 64) ? 64 : K;
  constexpr int NC = K / KC;
  constexpr int XP = KC + 4;
  __shared__ float Wl[KC * F];
  __shared__ float Xl[ROWS * XP];

  const int t = threadIdx.x;
  const int row0 = blockIdx.x * ROWS;

  const int cg = t % CG;
  const int rg = t / CG;
  float4 a0 = make_float4(0.f, 0.f, 0.f, 0.f);
  float4 a1 = make_float4(0.f, 0.f, 0.f, 0.f);
  float4 a2 = make_float4(0.f, 0.f, 0.f, 0.f);
  float4 a3 = make_float4(0.f, 0.f, 0.f, 0.f);

  for (int c = 0; c < NC; ++c) {
    __syncthreads();  // previous chunk reads done
    for (int i = t; i < KC * F / 4; i += 256)
      reinterpret_cast<float4*>(Wl)[i] =
          reinterpret_cast<const float4*>(W + c * KC * F)[i];
    for (int i = t; i < ROWS * KC / 4; i += 256) {
      int r = (i * 4) / KC, col = (i * 4) % KC;
      int row = row0 + r;
      float4 v = make_float4(0.f, 0.f, 0.f, 0.f);
      if (row < N)
        v = *reinterpret_cast<const float4*>(&X[(size_t)row * K + c * KC + col]);
      *reinterpret_cast<float4*>(&Xl[r * XP + col]) = v;
    }
    __syncthreads();
    if (rg < RG) {
      const float* xr = &Xl[rg * 4 * XP];
      const float* wb = &Wl[cg * 4];
#pragma unroll 2
      for (int k = 0; k < KC; k += 4) {
        float4 w0 = *reinterpret_cast<const float4*>(&wb[(k + 0) * F]);
        float4 w1 = *reinterpret_cast<const float4*>(&wb[(k + 1) * F]);
        float4 w2 = *reinterpret_cast<const float4*>(&wb[(k + 2) * F]);
        float4 w3 = *reinterpret_cast<const float4*>(&wb[(k + 3) * F]);
        float4 x0 = *reinterpret_cast<const float4*>(&xr[0 * XP + k]);
        float4 x1 = *reinterpret_cast<const float4*>(&xr[1 * XP + k]);
        float4 x2 = *reinterpret_cast<const float4*>(&xr[2 * XP + k]);
        float4 x3 = *reinterpret_cast<const float4*>(&xr[3 * XP + k]);
        a0.x = fmaf(x0.x, w0.x, a0.x); a0.y = fmaf(x0.x, w0.y, a0.y);
        a0.z = fmaf(x0.x, w0.z, a0.z); a0.w = fmaf(x0.x, w0.w, a0.w);
        a1.x = fmaf(x1.x, w0.x, a1.x); a1.y = fmaf(x1.x, w0.y, a1.y);
        a1.z = fmaf(x1.x, w0.z, a1.z); a1.w = fmaf(x1.x, w0.w, a1.w);
        a2.x = fmaf(x2.x, w0.x, a2.x); a2.y = fmaf(x2.x, w0.y, a2.y);
        a2.z = fmaf(x2.x, w0.z, a2.z); a2.w = fmaf(x2.x, w0.w, a2.w);
        a3.x = fmaf(x3.x, w0.x, a3.x); a3.y = fmaf(x3.x, w0.y, a3.y);
        a3.z = fmaf(x3.x, w0.z, a3.z); a3.w = fmaf(x3.x, w0.w, a3.w);

        a0.x = fmaf(x0.y, w1.x, a0.x); a0.y = fmaf(x0.y, w1.y, a0.y);
        a0.z = fmaf(x0.y, w1.z, a0.z); a0.w = fmaf(x0.y, w1.w, a0.w);
        a1.x = fmaf(x1.y, w1.x, a1.x); a1.y = fmaf(x1.y, w1.y, a1.y);
        a1.z = fmaf(x1.y, w1.z, a1.z); a1.w = fmaf(x1.y, w1.w, a1.w);
        a2.x = fmaf(x2.y, w1.x, a2.x); a2.y = fmaf(x2.y, w1.y, a2.y);
        a2.z = fmaf(x2.y, w1.z, a2.z); a2.w = fmaf(x2.y, w1.w, a2.w);
        a3.x = fmaf(x3.y, w1.x, a3.x); a3.y = fmaf(x3.y, w1.y, a3.y);
        a3.z = fmaf(x3.y, w1.z, a3.z); a3.w = fmaf(x3.y, w1.w, a3.w);

        a0.x = fmaf(x0.z, w2.x, a0.x); a0.y = fmaf(x0.z, w2.y, a0.y);
        a0.z = fmaf(x0.z, w2.z, a0.z); a0.w = fmaf(x0.z, w2.w, a0.w);
        a1.x = fmaf(x1.z, w2.x, a1.x); a1.y = fmaf(x1.z, w2.y, a1.y);
        a1.z = fmaf(x1.z, w2.z, a1.z); a1.w = fmaf(x1.z, w2.w, a1.w);
        a2.x = fmaf(x2.z, w2.x, a2.x); a2.y = fmaf(x2.z, w2.y, a2.y);
        a2.z = fmaf(x2.z, w2.z, a2.z); a2.w = fmaf(x2.z, w2.w, a2.w);
        a3.x = fmaf(x3.z, w2.x, a3.x); a3.y = fmaf(x3.z, w2.y, a3.y);
        a3.z = fmaf(x3.z, w2.z, a3.z); a3.w = fmaf(x3.z, w2.w, a3.w);

        a0.x = fmaf(x0.w, w3.x, a0.x); a0.y = fmaf(x0.w, w3.y, a0.y);
        a0.z = fmaf(x0.w, w3.z, a0.z); a0.w = fmaf(x0.w, w3.w, a0.w);
        a1.x = fmaf(x1.w, w3.x, a1.x); a1.y = fmaf(x1.w, w3.y, a1.y);
        a1.z = fmaf(x1.w, w3.z, a1.z); a1.w = fmaf(x1.w, w3.w, a1.w);
        a2.x = fmaf(x2.w, w3.x, a2.x); a2.y = fmaf(x2.w, w3.y, a2.y);
        a2.z = fmaf(x2.w, w3.z, a2.z); a2.w = fmaf(x2.w, w3.w, a2.w);
        a3.x = fmaf(x3.w, w3.x, a3.x); a3.y = fmaf(x3.w, w3.y, a3.y);
        a3.z = fmaf(x3.w, w3.z, a3.z); a3.w = fmaf(x3.w, w3.w, a3.w);
      }
    }
  }

  if (rg < RG) {
    const int col = cg * 4;
    const int row = row0 + rg * 4;
#pragma unroll
    for (int r = 0; r < 4; ++r) {
      if (row + r < N) {
        float4 v = (r == 0) ? a0 : (r == 1) ? a1 : (r == 2) ? a2 : a3;
        float s = dinv[row + r];
        half4 o;
        o.a = __floats2half2_rn(v.x * s, v.y * s);
        o.b = __floats2half2_rn(v.z * s, v.w * s);
        *reinterpret_cast<half4*>(&Hh[(size_t)(row + r) * F + col]) = o;
      }
    }
  }
}

// G[i,:] = BN/ReLU( dinv[i] * sum_p Hh[csr_src[p],:] + bias ).  1 wave/node,
// 4x16-lane groups take every 4th edge; lane gl holds features gl*4..gl*4+3
// (half4 = 8B load, 16 lanes = full fp16 row); unroll x2; shuffle reduce.
template <int F, bool BNR>
__global__ __launch_bounds__(256) void k_agg(const __half* __restrict__ H,
                                             float* __restrict__ G,
                                             const int* __restrict__ rowptr,
                                             const int* __restrict__ csr_src,
                                             const float* __restrict__ dinv,
                                             const float* __restrict__ bias,
                                             const float* __restrict__ gam,
                                             const float* __restrict__ bet,
                                             const float* __restrict__ mu,
                                             const float* __restrict__ var, int N) {
  constexpr int LPG = F / 4;
  int node = (blockIdx.x * 256 + threadIdx.x) >> 6;
  int lane = threadIdx.x & 63;
  if (node >= N) return;
  int g = lane >> 4, gl = lane & 15;
  bool active = gl < LPG;
  int p0 = rowptr[node], p1 = rowptr[node + 1];
  float4 a0 = make_float4(0.f, 0.f, 0.f, 0.f);
  float4 a1 = make_float4(0.f, 0.f, 0.f, 0.f);
  int p = p0 + g;
  for (; p + 4 < p1; p += 8) {
    int s0 = csr_src[p];
    int s1 = csr_src[p + 4];
    if (active) {
      half4 h0 = *reinterpret_cast<const half4*>(&H[(size_t)s0 * F + gl * 4]);
      half4 h1 = *reinterpret_cast<const half4*>(&H[(size_t)s1 * F + gl * 4]);
      float2 l0 = __half22float2(h0.a), u0 = __half22float2(h0.b);
      float2 l1 = __half22float2(h1.a), u1 = __half22float2(h1.b);
      a0.x += l0.x; a0.y += l0.y; a0.z += u0.x; a0.w += u0.y;
      a1.x += l1.x; a1.y += l1.y; a1.z += u1.x; a1.w += u1.y;
    }
  }
  if (p < p1) {
    int s0 = csr_src[p];
    if (active) {
      half4 h0 = *reinterpret_cast<const half4*>(&H[(size_t)s0 * F + gl * 4]);
      float2 l0 = __half22float2(h0.a), u0 = __half22float2(h0.b);
      a0.x += l0.x; a0.y += l0.y; a0.z += u0.x; a0.w += u0.y;
    }
  }
  a0.x += a1.x; a0.y += a1.y; a0.z += a1.z; a0.w += a1.w;
#pragma unroll
  for (int off = 16; off <= 32; off <<= 1) {
    a0.x += __shfl_xor(a0.x, off);
    a0.y += __shfl_xor(a0.y, off);
    a0.z += __shfl_xor(a0.z, off);
    a0.w += __shfl_xor(a0.w, off);
  }
  if (g == 0 && active) {
    int f = gl * 4;
    float di = dinv[node];
    float4 y;
    y.x = fmaf(di, a0.x, bias[f + 0]);
    y.y = fmaf(di, a0.y, bias[f + 1]);
    y.z = fmaf(di, a0.z, bias[f + 2]);
    y.w = fmaf(di, a0.w, bias[f + 3]);
    if (BNR) {
      y.x = fmaxf((y.x - mu[f + 0]) * rsqrtf(var[f + 0] + 1e-5f) * gam[f + 0] + bet[f + 0], 0.f);
      y.y = fmaxf((y.y - mu[f + 1]) * rsqrtf(var[f + 1] + 1e-5f) * gam[f + 1] + bet[f + 1], 0.f);
      y.z = fmaxf((y.z - mu[f + 2]) * rsqrtf(var[f + 2] + 1e-5f) * gam[f + 2] + bet[f + 2], 0.f);
      y.w = fmaxf((y.w - mu[f + 3]) * rsqrtf(var[f + 3] + 1e-5f) * gam[f + 3] + bet[f + 3], 0.f);
    }
    *reinterpret_cast<float4*>(&G[(size_t)node * F + f]) = y;
  }
}

extern "C" void kernel_launch(void* const* d_in, const int* in_sizes, int n_in,
                              void* d_out, int out_size, void* d_ws, size_t ws_size,
                              hipStream_t stream) {
  const float* x  = (const float*)d_in[0];
  const int*   ei = (const int*)d_in[1];
  const float* W1 = (const float*)d_in[2];
  const float* b1 = (const float*)d_in[3];
  const float* W2 = (const float*)d_in[4];
  const float* b2 = (const float*)d_in[5];
  const float* W3 = (const float*)d_in[6];
  const float* b3 = (const float*)d_in[7];
  const float* g1 = (const float*)d_in[8];
  const float* be1 = (const float*)d_in[9];
  const float* m1 = (const float*)d_in[10];
  const float* v1 = (const float*)d_in[11];
  const float* g2 = (const float*)d_in[12];
  const float* be2 = (const float*)d_in[13];
  const float* m2 = (const float*)d_in[14];
  const float* v2 = (const float*)d_in[15];

  const int N = in_sizes[0] / 128;  // 100000
  const int E = in_sizes[1] / 2;    // 1000000
  const int* src = ei;
  const int* dst = ei + E;

  char* w = (char*)d_ws;
  size_t off = 0;
  auto take = [&](size_t bytes) -> void* {
    void* p = w + off;
    off += (bytes + 511) & ~size_t(511);
    return p;
  };
  int*    deg     = (int*)take((size_t)N * 4);
  size_t  zeroB   = off;  // only deg needs zeroing
  int*    fillc   = (int*)take((size_t)N * 4);
  int*    rowptr  = (int*)take(((size_t)N + 1) * 4);
  float*  dinv    = (float*)take((size_t)N * 4);
  int*    bsum    = (int*)take((size_t)SCAN_T * 4);
  int*    csr_src = (int*)take((size_t)E * 4);
  __half* Hh      = (__half*)take((size_t)N * 64 * 2);
  float*  Gf      = (float*)take((size_t)N * 64 * 4);
  if (off > ws_size) return;

  const int nb = (N + SCAN_B - 1) / SCAN_B;           // 49
  const int PS = (N + NPART - 1) / NPART;             // 12500
  const int nchunks = (E + ECHUNK - 1) / ECHUNK;      // 489
  const int partGrid = nchunks * NPART;               // 3912

  hipMemsetAsync(d_ws, 0, zeroB, stream);
  k_count_deg<<<partGrid, 256, 0, stream>>>(dst, deg, E, PS);
  k_scan1<<<nb, SCAN_T, 0, stream>>>(deg, rowptr, bsum, N);
  k_scan2<<<1, SCAN_T, 0, stream>>>(bsum, nb);
  k_scan3<<<(N + 255) / 256, 256, 0, stream>>>(rowptr, fillc, bsum, deg, dinv, N, E);
  k_fill<<<partGrid, 256, 0, stream>>>(src, dst, fillc, csr_src, E, PS);

  // layer 1
  k_gemm<128, 64><<<(N + 63) / 64, 256, 0, stream>>>(x, W1, dinv, Hh, N);
  k_agg<64, true><<<(N + 3) / 4, 256, 0, stream>>>(Hh, Gf, rowptr, csr_src,
                                                   dinv, b1, g1, be1, m1, v1, N);
  // layer 2
  k_gemm<64, 64><<<(N + 63) / 64, 256, 0, stream>>>(Gf, W2, dinv, Hh, N);
  k_agg<64, true><<<(N + 3) / 4, 256, 0, stream>>>(Hh, Gf, rowptr, csr_src,
                                                   dinv, b2, g2, be2, m2, v2, N);
  // output layer
  k_gemm<64, 40><<<(N + 99) / 100, 256, 0, stream>>>(Gf, W3, dinv, Hh, N);
  k_agg<40, false><<<(N + 3) / 4, 256, 0, stream>>>(
      Hh, (float*)d_out, rowptr, csr_src, dinv, b3, nullptr, nullptr, nullptr,
      nullptr, N);
}

// Round 10
// 287.205 us; speedup vs baseline: 1.0290x; 1.0290x over previous
//
#include <hip/hip_runtime.h>
#include <hip/hip_fp16.h>
#include <type_traits>

// ---------------------------------------------------------------------------
// 3-layer GCN (PyG GCNConv, add_self_loops=False) on MI355X.
// Pipeline (11 launches, dependency-driven fusion):
//   memset(deg)
//   fused1: [gemm1 (x@W1 -> Hh unscaled, fp16)]  ||  [count_deg (partitioned)]
//   scan1/scan2/scan3 (rowptr, dinv, fillc)
//   fused2: [fill CSR (partitioned)]  ||  [scaleH: Hh *= dinv[row]]
//   agg1 -> Gh fp16 ; gemm2(Gh) -> Hh ; agg2 -> Gh ; gemm3(Gh) -> Hh40 ;
//   agg3 -> d_out fp32
// Round-9 lessons: fill write-amp is structural (~52us floor after 3 attempts)
// -> hide independent work instead (count under gemm1, scale under fill).
// fp16 G buffer saves ~50MB across agg-write/gemm-read.
// ---------------------------------------------------------------------------

struct half4 { __half2 a, b; };
struct half8 { half4 lo, hi; };
typedef int iv4 __attribute__((ext_vector_type(4)));

constexpr int SCAN_T = 256;
constexpr int SCAN_E = 8;
constexpr int SCAN_B = SCAN_T * SCAN_E;
constexpr int NPART = 8;
constexpr int ECHUNK = 2048;

// ---------------- edge-phase device bodies ----------------

__device__ __forceinline__ void count_body(int bid, const int* __restrict__ dst,
                                           int* __restrict__ deg, int E, int PS) {
  const int p = bid & 7;
  const int lo = p * PS, hi = lo + PS;
  const int base = (bid >> 3) * ECHUNK + threadIdx.x * 4;
#pragma unroll
  for (int h = 0; h < 2; ++h) {
    int e = base + h * 1024;
    if (e + 3 < E) {
      iv4 d4 = __builtin_nontemporal_load(reinterpret_cast<const iv4*>(&dst[e]));
      if (d4.x >= lo && d4.x < hi) atomicAdd(&deg[d4.x], 1);
      if (d4.y >= lo && d4.y < hi) atomicAdd(&deg[d4.y], 1);
      if (d4.z >= lo && d4.z < hi) atomicAdd(&deg[d4.z], 1);
      if (d4.w >= lo && d4.w < hi) atomicAdd(&deg[d4.w], 1);
    } else {
      for (int j = 0; j < 4; ++j) {
        int ee = e + j;
        if (ee < E) {
          int d = dst[ee];
          if (d >= lo && d < hi) atomicAdd(&deg[d], 1);
        }
      }
    }
  }
}

__device__ __forceinline__ void fill_body(int bid, const int* __restrict__ src,
                                          const int* __restrict__ dst,
                                          int* __restrict__ fillc,
                                          int* __restrict__ csr_src, int E, int PS) {
  const int p = bid & 7;
  const int lo = p * PS, hi = lo + PS;
  const int base = (bid >> 3) * ECHUNK + threadIdx.x * 4;
#pragma unroll
  for (int h = 0; h < 2; ++h) {
    int e = base + h * 1024;
    if (e + 3 < E) {
      iv4 d4 = __builtin_nontemporal_load(reinterpret_cast<const iv4*>(&dst[e]));
      iv4 s4 = __builtin_nontemporal_load(reinterpret_cast<const iv4*>(&src[e]));
      if (d4.x >= lo && d4.x < hi) csr_src[atomicAdd(&fillc[d4.x], 1)] = s4.x;
      if (d4.y >= lo && d4.y < hi) csr_src[atomicAdd(&fillc[d4.y], 1)] = s4.y;
      if (d4.z >= lo && d4.z < hi) csr_src[atomicAdd(&fillc[d4.z], 1)] = s4.z;
      if (d4.w >= lo && d4.w < hi) csr_src[atomicAdd(&fillc[d4.w], 1)] = s4.w;
    } else {
      for (int j = 0; j < 4; ++j) {
        int ee = e + j;
        if (ee < E) {
          int d = dst[ee];
          if (d >= lo && d < hi) csr_src[atomicAdd(&fillc[d], 1)] = src[ee];
        }
      }
    }
  }
}

// Hh[idx*8 .. idx*8+7] *= dinv[row]   (8 halves/thread, one row = 8 groups)
__device__ __forceinline__ void scale_body(int bid, __half* __restrict__ Hh,
                                           const float* __restrict__ dinv, int N) {
  int idx = bid * 256 + threadIdx.x;
  if (idx >= N * 8) return;
  float s = dinv[idx >> 3];
  half8 v = *reinterpret_cast<half8*>(&Hh[(size_t)idx * 8]);
  float2 f;
  f = __half22float2(v.lo.a); v.lo.a = __floats2half2_rn(f.x * s, f.y * s);
  f = __half22float2(v.lo.b); v.lo.b = __floats2half2_rn(f.x * s, f.y * s);
  f = __half22float2(v.hi.a); v.hi.a = __floats2half2_rn(f.x * s, f.y * s);
  f = __half22float2(v.hi.b); v.hi.b = __floats2half2_rn(f.x * s, f.y * s);
  *reinterpret_cast<half8*>(&Hh[(size_t)idx * 8]) = v;
}

// ---------------- scans ----------------

__global__ __launch_bounds__(SCAN_T) void k_scan1(const int* __restrict__ deg,
                                                  int* __restrict__ pre,
                                                  int* __restrict__ bsum, int N) {
  __shared__ int ls[SCAN_T];
  int t = threadIdx.x;
  int base = blockIdx.x * SCAN_B + t * SCAN_E;
  int v[SCAN_E];
  int s = 0;
#pragma unroll
  for (int j = 0; j < SCAN_E; ++j) {
    int idx = base + j;
    v[j] = (idx < N) ? deg[idx] : 0;
    s += v[j];
  }
  ls[t] = s;
  __syncthreads();
  for (int off = 1; off < SCAN_T; off <<= 1) {
    int x = 0;
    if (t >= off) x = ls[t - off];
    __syncthreads();
    ls[t] += x;
    __syncthreads();
  }
  if (t == SCAN_T - 1) bsum[blockIdx.x] = ls[t];
  int run = (t > 0) ? ls[t - 1] : 0;
#pragma unroll
  for (int j = 0; j < SCAN_E; ++j) {
    int idx = base + j;
    if (idx < N) pre[idx] = run;
    run += v[j];
  }
}

__global__ __launch_bounds__(SCAN_T) void k_scan2(int* __restrict__ bsum, int nb) {
  __shared__ int ls[SCAN_T];
  int t = threadIdx.x;
  ls[t] = (t < nb) ? bsum[t] : 0;
  __syncthreads();
  for (int off = 1; off < SCAN_T; off <<= 1) {
    int x = 0;
    if (t >= off) x = ls[t - off];
    __syncthreads();
    ls[t] += x;
    __syncthreads();
  }
  if (t < nb) bsum[t] = (t > 0) ? ls[t - 1] : 0;
}

__global__ __launch_bounds__(256) void k_scan3(int* __restrict__ rowptr,
                                               int* __restrict__ fillc,
                                               const int* __restrict__ bsum,
                                               const int* __restrict__ deg,
                                               float* __restrict__ dinv,
                                               int N, int E) {
  int i = blockIdx.x * 256 + threadIdx.x;
  if (i < N) {
    int r = rowptr[i] + bsum[i / SCAN_B];
    rowptr[i] = r;
    fillc[i] = r;
    int d = deg[i];
    dinv[i] = (d > 0) ? rsqrtf((float)d) : 0.f;
  }
  if (i == 0) rowptr[N] = E;
}

// ---------------- GEMM ----------------
// Hh = [SCALE? dinv[row]:1] * (X@W) as fp16.  Thread = 4 rows x 4 cols.
template <int K, int F, typename Tin, bool SCALE>
__device__ __forceinline__ void gemm_body(int bid, const Tin* __restrict__ X,
                                          const float* __restrict__ W,
                                          const float* __restrict__ dinv,
                                          __half* __restrict__ Hh, int N) {
  constexpr int CG = F / 4;
  constexpr int RG = 256 / CG;
  constexpr int ROWS = RG * 4;
  constexpr int KC = (K > 64) ? 64 : K;
  constexpr int NC = K / KC;
  constexpr int XP = KC + 4;
  __shared__ float Wl[KC * F];
  __shared__ float Xl[ROWS * XP];

  const int t = threadIdx.x;
  const int row0 = bid * ROWS;
  const int cg = t % CG;
  const int rg = t / CG;
  float4 a0 = make_float4(0.f, 0.f, 0.f, 0.f);
  float4 a1 = make_float4(0.f, 0.f, 0.f, 0.f);
  float4 a2 = make_float4(0.f, 0.f, 0.f, 0.f);
  float4 a3 = make_float4(0.f, 0.f, 0.f, 0.f);

  for (int c = 0; c < NC; ++c) {
    __syncthreads();
    for (int i = t; i < KC * F / 4; i += 256)
      reinterpret_cast<float4*>(Wl)[i] =
          reinterpret_cast<const float4*>(W + c * KC * F)[i];
    for (int i = t; i < ROWS * KC / 4; i += 256) {
      int r = (i * 4) / KC, col = (i * 4) % KC;
      int row = row0 + r;
      float4 v = make_float4(0.f, 0.f, 0.f, 0.f);
      if (row < N) {
        if constexpr (std::is_same<Tin, float>::value) {
          v = *reinterpret_cast<const float4*>(&X[(size_t)row * K + c * KC + col]);
        } else {
          half4 hv = *reinterpret_cast<const half4*>(&X[(size_t)row * K + c * KC + col]);
          float2 lo = __half22float2(hv.a), hi = __half22float2(hv.b);
          v = make_float4(lo.x, lo.y, hi.x, hi.y);
        }
      }
      *reinterpret_cast<float4*>(&Xl[r * XP + col]) = v;
    }
    __syncthreads();
    if (rg < RG) {
      const float* xr = &Xl[rg * 4 * XP];
      const float* wb = &Wl[cg * 4];
#pragma unroll 2
      for (int k = 0; k < KC; k += 4) {
        float4 w0 = *reinterpret_cast<const float4*>(&wb[(k + 0) * F]);
        float4 w1 = *reinterpret_cast<const float4*>(&wb[(k + 1) * F]);
        float4 w2 = *reinterpret_cast<const float4*>(&wb[(k + 2) * F]);
        float4 w3 = *reinterpret_cast<const float4*>(&wb[(k + 3) * F]);
        float4 x0 = *reinterpret_cast<const float4*>(&xr[0 * XP + k]);
        float4 x1 = *reinterpret_cast<const float4*>(&xr[1 * XP + k]);
        float4 x2 = *reinterpret_cast<const float4*>(&xr[2 * XP + k]);
        float4 x3 = *reinterpret_cast<const float4*>(&xr[3 * XP + k]);
        a0.x = fmaf(x0.x, w0.x, a0.x); a0.y = fmaf(x0.x, w0.y, a0.y);
        a0.z = fmaf(x0.x, w0.z, a0.z); a0.w = fmaf(x0.x, w0.w, a0.w);
        a1.x = fmaf(x1.x, w0.x, a1.x); a1.y = fmaf(x1.x, w0.y, a1.y);
        a1.z = fmaf(x1.x, w0.z, a1.z); a1.w = fmaf(x1.x, w0.w, a1.w);
        a2.x = fmaf(x2.x, w0.x, a2.x); a2.y = fmaf(x2.x, w0.y, a2.y);
        a2.z = fmaf(x2.x, w0.z, a2.z); a2.w = fmaf(x2.x, w0.w, a2.w);
        a3.x = fmaf(x3.x, w0.x, a3.x); a3.y = fmaf(x3.x, w0.y, a3.y);
        a3.z = fmaf(x3.x, w0.z, a3.z); a3.w = fmaf(x3.x, w0.w, a3.w);

        a0.x = fmaf(x0.y, w1.x, a0.x); a0.y = fmaf(x0.y, w1.y, a0.y);
        a0.z = fmaf(x0.y, w1.z, a0.z); a0.w = fmaf(x0.y, w1.w, a0.w);
        a1.x = fmaf(x1.y, w1.x, a1.x); a1.y = fmaf(x1.y, w1.y, a1.y);
        a1.z = fmaf(x1.y, w1.z, a1.z); a1.w = fmaf(x1.y, w1.w, a1.w);
        a2.x = fmaf(x2.y, w1.x, a2.x); a2.y = fmaf(x2.y, w1.y, a2.y);
        a2.z = fmaf(x2.y, w1.z, a2.z); a2.w = fmaf(x2.y, w1.w, a2.w);
        a3.x = fmaf(x3.y, w1.x, a3.x); a3.y = fmaf(x3.y, w1.y, a3.y);
        a3.z = fmaf(x3.y, w1.z, a3.z); a3.w = fmaf(x3.y, w1.w, a3.w);

        a0.x = fmaf(x0.z, w2.x, a0.x); a0.y = fmaf(x0.z, w2.y, a0.y);
        a0.z = fmaf(x0.z, w2.z, a0.z); a0.w = fmaf(x0.z, w2.w, a0.w);
        a1.x = fmaf(x1.z, w2.x, a1.x); a1.y = fmaf(x1.z, w2.y, a1.y);
        a1.z = fmaf(x1.z, w2.z, a1.z); a1.w = fmaf(x1.z, w2.w, a1.w);
        a2.x = fmaf(x2.z, w2.x, a2.x); a2.y = fmaf(x2.z, w2.y, a2.y);
        a2.z = fmaf(x2.z, w2.z, a2.z); a2.w = fmaf(x2.z, w2.w, a2.w);
        a3.x = fmaf(x3.z, w2.x, a3.x); a3.y = fmaf(x3.z, w2.y, a3.y);
        a3.z = fmaf(x3.z, w2.z, a3.z); a3.w = fmaf(x3.z, w2.w, a3.w);

        a0.x = fmaf(x0.w, w3.x, a0.x); a0.y = fmaf(x0.w, w3.y, a0.y);
        a0.z = fmaf(x0.w, w3.z, a0.z); a0.w = fmaf(x0.w, w3.w, a0.w);
        a1.x = fmaf(x1.w, w3.x, a1.x); a1.y = fmaf(x1.w, w3.y, a1.y);
        a1.z = fmaf(x1.w, w3.z, a1.z); a1.w = fmaf(x1.w, w3.w, a1.w);
        a2.x = fmaf(x2.w, w3.x, a2.x); a2.y = fmaf(x2.w, w3.y, a2.y);
        a2.z = fmaf(x2.w, w3.z, a2.z); a2.w = fmaf(x2.w, w3.w, a2.w);
        a3.x = fmaf(x3.w, w3.x, a3.x); a3.y = fmaf(x3.w, w3.y, a3.y);
        a3.z = fmaf(x3.w, w3.z, a3.z); a3.w = fmaf(x3.w, w3.w, a3.w);
      }
    }
  }

  if (rg < RG) {
    const int col = cg * 4;
    const int row = row0 + rg * 4;
#pragma unroll
    for (int r = 0; r < 4; ++r) {
      if (row + r < N) {
        float4 v = (r == 0) ? a0 : (r == 1) ? a1 : (r == 2) ? a2 : a3;
        float s = 1.f;
        if constexpr (SCALE) s = dinv[row + r];
        half4 o;
        o.a = __floats2half2_rn(v.x * s, v.y * s);
        o.b = __floats2half2_rn(v.z * s, v.w * s);
        *reinterpret_cast<half4*>(&Hh[(size_t)(row + r) * F + col]) = o;
      }
    }
  }
}

template <int K, int F>
__global__ __launch_bounds__(256) void k_gemm_h(const __half* __restrict__ X,
                                                const float* __restrict__ W,
                                                const float* __restrict__ dinv,
                                                __half* __restrict__ Hh, int N) {
  gemm_body<K, F, __half, true>(blockIdx.x, X, W, dinv, Hh, N);
}

// fused1: gemm1 (unscaled) || count_deg
__global__ __launch_bounds__(256) void k_fused1(const float* __restrict__ X,
                                                const float* __restrict__ W,
                                                __half* __restrict__ Hh, int N,
                                                int gemmBlocks,
                                                const int* __restrict__ dst,
                                                int* __restrict__ deg, int E, int PS) {
  int bid = (int)blockIdx.x;
  if (bid < gemmBlocks)
    gemm_body<128, 64, float, false>(bid, X, W, nullptr, Hh, N);
  else
    count_body(bid - gemmBlocks, dst, deg, E, PS);
}

// fused2: fill || scaleH
__global__ __launch_bounds__(256) void k_fused2(const int* __restrict__ src,
                                                const int* __restrict__ dst,
                                                int* __restrict__ fillc,
                                                int* __restrict__ csr_src, int E, int PS,
                                                int fillBlocks,
                                                __half* __restrict__ Hh,
                                                const float* __restrict__ dinv, int N) {
  int bid = (int)blockIdx.x;
  if (bid < fillBlocks)
    fill_body(bid, src, dst, fillc, csr_src, E, PS);
  else
    scale_body(bid - fillBlocks, Hh, dinv, N);
}

// ---------------- aggregation ----------------
// G[i,:] = BN/ReLU( dinv[i] * sum_p Hh[csr_src[p],:] + bias ), output Tout.
template <int F, bool BNR, typename Tout>
__global__ __launch_bounds__(256) void k_agg(const __half* __restrict__ H,
                                             Tout* __restrict__ G,
                                             const int* __restrict__ rowptr,
                                             const int* __restrict__ csr_src,
                                             const float* __restrict__ dinv,
                                             const float* __restrict__ bias,
                                             const float* __restrict__ gam,
                                             const float* __restrict__ bet,
                                             const float* __restrict__ mu,
                                             const float* __restrict__ var, int N) {
  constexpr int LPG = F / 4;
  int node = (blockIdx.x * 256 + threadIdx.x) >> 6;
  int lane = threadIdx.x & 63;
  if (node >= N) return;
  int g = lane >> 4, gl = lane & 15;
  bool active = gl < LPG;
  int p0 = rowptr[node], p1 = rowptr[node + 1];
  float4 a0 = make_float4(0.f, 0.f, 0.f, 0.f);
  float4 a1 = make_float4(0.f, 0.f, 0.f, 0.f);
  int p = p0 + g;
  for (; p + 4 < p1; p += 8) {
    int s0 = csr_src[p];
    int s1 = csr_src[p + 4];
    if (active) {
      half4 h0 = *reinterpret_cast<const half4*>(&H[(size_t)s0 * F + gl * 4]);
      half4 h1 = *reinterpret_cast<const half4*>(&H[(size_t)s1 * F + gl * 4]);
      float2 l0 = __half22float2(h0.a), u0 = __half22float2(h0.b);
      float2 l1 = __half22float2(h1.a), u1 = __half22float2(h1.b);
      a0.x += l0.x; a0.y += l0.y; a0.z += u0.x; a0.w += u0.y;
      a1.x += l1.x; a1.y += l1.y; a1.z += u1.x; a1.w += u1.y;
    }
  }
  if (p < p1) {
    int s0 = csr_src[p];
    if (active) {
      half4 h0 = *reinterpret_cast<const half4*>(&H[(size_t)s0 * F + gl * 4]);
      float2 l0 = __half22float2(h0.a), u0 = __half22float2(h0.b);
      a0.x += l0.x; a0.y += l0.y; a0.z += u0.x; a0.w += u0.y;
    }
  }
  a0.x += a1.x; a0.y += a1.y; a0.z += a1.z; a0.w += a1.w;
#pragma unroll
  for (int off = 16; off <= 32; off <<= 1) {
    a0.x += __shfl_xor(a0.x, off);
    a0.y += __shfl_xor(a0.y, off);
    a0.z += __shfl_xor(a0.z, off);
    a0.w += __shfl_xor(a0.w, off);
  }
  if (g == 0 && active) {
    int f = gl * 4;
    float di = dinv[node];
    float4 y;
    y.x = fmaf(di, a0.x, bias[f + 0]);
    y.y = fmaf(di, a0.y, bias[f + 1]);
    y.z = fmaf(di, a0.z, bias[f + 2]);
    y.w = fmaf(di, a0.w, bias[f + 3]);
    if (BNR) {
      y.x = fmaxf((y.x - mu[f + 0]) * rsqrtf(var[f + 0] + 1e-5f) * gam[f + 0] + bet[f + 0], 0.f);
      y.y = fmaxf((y.y - mu[f + 1]) * rsqrtf(var[f + 1] + 1e-5f) * gam[f + 1] + bet[f + 1], 0.f);
      y.z = fmaxf((y.z - mu[f + 2]) * rsqrtf(var[f + 2] + 1e-5f) * gam[f + 2] + bet[f + 2], 0.f);
      y.w = fmaxf((y.w - mu[f + 3]) * rsqrtf(var[f + 3] + 1e-5f) * gam[f + 3] + bet[f + 3], 0.f);
    }
    if constexpr (std::is_same<Tout, __half>::value) {
      half4 o;
      o.a = __floats2half2_rn(y.x, y.y);
      o.b = __floats2half2_rn(y.z, y.w);
      *reinterpret_cast<half4*>(&G[(size_t)node * F + f]) = o;
    } else {
      *reinterpret_cast<float4*>(&G[(size_t)node * F + f]) = y;
    }
  }
}

extern "C" void kernel_launch(void* const* d_in, const int* in_sizes, int n_in,
                              void* d_out, int out_size, void* d_ws, size_t ws_size,
                              hipStream_t stream) {
  const float* x  = (const float*)d_in[0];
  const int*   ei = (const int*)d_in[1];
  const float* W1 = (const float*)d_in[2];
  const float* b1 = (const float*)d_in[3];
  const float* W2 = (const float*)d_in[4];
  const float* b2 = (const float*)d_in[5];
  const float* W3 = (const float*)d_in[6];
  const float* b3 = (const float*)d_in[7];
  const float* g1 = (const float*)d_in[8];
  const float* be1 = (const float*)d_in[9];
  const float* m1 = (const float*)d_in[10];
  const float* v1 = (const float*)d_in[11];
  const float* g2 = (const float*)d_in[12];
  const float* be2 = (const float*)d_in[13];
  const float* m2 = (const float*)d_in[14];
  const float* v2 = (const float*)d_in[15];

  const int N = in_sizes[0] / 128;  // 100000
  const int E = in_sizes[1] / 2;    // 1000000
  const int* src = ei;
  const int* dst = ei + E;

  char* w = (char*)d_ws;
  size_t off = 0;
  auto take = [&](size_t bytes) -> void* {
    void* p = w + off;
    off += (bytes + 511) & ~size_t(511);
    return p;
  };
  int*    deg     = (int*)take((size_t)N * 4);
  size_t  zeroB   = off;  // only deg needs zeroing
  int*    fillc   = (int*)take((size_t)N * 4);
  int*    rowptr  = (int*)take(((size_t)N + 1) * 4);
  float*  dinv    = (float*)take((size_t)N * 4);
  int*    bsum    = (int*)take((size_t)SCAN_T * 4);
  int*    csr_src = (int*)take((size_t)E * 4);
  __half* Hh      = (__half*)take((size_t)N * 64 * 2);
  __half* Gh      = (__half*)take((size_t)N * 64 * 2);
  if (off > ws_size) return;

  const int nb = (N + SCAN_B - 1) / SCAN_B;           // 49
  const int PS = (N + NPART - 1) / NPART;             // 12500
  const int nchunks = (E + ECHUNK - 1) / ECHUNK;      // 489
  const int partGrid = nchunks * NPART;               // 3912
  const int gemm1Blocks = (N + 63) / 64;              // 1563
  const int scaleBlocks = (N * 8 + 255) / 256;        // 3125

  hipMemsetAsync(d_ws, 0, zeroB, stream);
  // gemm1 (unscaled) || count_deg
  k_fused1<<<gemm1Blocks + partGrid, 256, 0, stream>>>(x, W1, Hh, N, gemm1Blocks,
                                                       dst, deg, E, PS);
  k_scan1<<<nb, SCAN_T, 0, stream>>>(deg, rowptr, bsum, N);
  k_scan2<<<1, SCAN_T, 0, stream>>>(bsum, nb);
  k_scan3<<<(N + 255) / 256, 256, 0, stream>>>(rowptr, fillc, bsum, deg, dinv, N, E);
  // fill || scaleH (Hh *= dinv[row])
  k_fused2<<<partGrid + scaleBlocks, 256, 0, stream>>>(src, dst, fillc, csr_src,
                                                       E, PS, partGrid, Hh, dinv, N);

  // layer 1 aggregation -> Gh (fp16)
  k_agg<64, true, __half><<<(N + 3) / 4, 256, 0, stream>>>(
      Hh, Gh, rowptr, csr_src, dinv, b1, g1, be1, m1, v1, N);
  // layer 2
  k_gemm_h<64, 64><<<(N + 63) / 64, 256, 0, stream>>>(Gh, W2, dinv, Hh, N);
  k_agg<64, true, __half><<<(N + 3) / 4, 256, 0, stream>>>(
      Hh, Gh, rowptr, csr_src, dinv, b2, g2, be2, m2, v2, N);
  // output layer
  k_gemm_h<64, 40><<<(N + 99) / 100, 256, 0, stream>>>(Gh, W3, dinv, Hh, N);
  k_agg<40, false, float><<<(N + 3) / 4, 256, 0, stream>>>(
      Hh, (float*)d_out, rowptr, csr_src, dinv, b3, nullptr, nullptr, nullptr,
      nullptr, N);
}

// Round 12
// 284.381 us; speedup vs baseline: 1.0392x; 1.0099x over previous
//
#include <hip/hip_runtime.h>
#include <hip/hip_fp16.h>
#include <type_traits>

// ---------------------------------------------------------------------------
// 3-layer GCN (PyG GCNConv, add_self_loops=False) on MI355X.
// Pipeline (7 launches):
//   memset(deg)
//   fused1: 3 gemm1-blocks : 4 count-worker blocks (modulo interleave).
//           count workers: partition p = widx&7, chunks strided (static, no
//           XCC_ID — round-11 XCC work-stealing faulted on coverage gaps).
//   scan1/scan2/scan3 (rowptr, dinv, fillc)
//   fused2: 3 scale-blocks : 2 fill-worker blocks (same static scheme)
//   agg1 -> Gh fp16 ; gemm2 -> Hh ; agg2 -> Gh ; gemm3 -> Hh40 ; agg3 -> out
// ---------------------------------------------------------------------------

struct half4 { __half2 a, b; };
struct half8 { half4 lo, hi; };
typedef int iv4 __attribute__((ext_vector_type(4)));
typedef short sv8 __attribute__((ext_vector_type(8)));

constexpr int SCAN_T = 256;
constexpr int SCAN_E = 8;
constexpr int SCAN_B = SCAN_T * SCAN_E;
constexpr int NPART = 8;
constexpr int ECHUNK = 2048;
constexpr int NWORK = 2048;           // edge workers per fused launch
constexpr int WSTRIDE = NWORK / 8;    // chunk stride per partition (256)

// ---------------- edge-phase bodies ----------------

__device__ __forceinline__ void count_chunk(int c, int lo, int hi,
                                            const int* __restrict__ dst,
                                            int* __restrict__ deg, int E) {
  const int base = c * ECHUNK + threadIdx.x * 4;
#pragma unroll
  for (int h = 0; h < 2; ++h) {
    int e = base + h * 1024;
    if (e + 3 < E) {
      iv4 d4 = __builtin_nontemporal_load(reinterpret_cast<const iv4*>(&dst[e]));
      if (d4.x >= lo && d4.x < hi) atomicAdd(&deg[d4.x], 1);
      if (d4.y >= lo && d4.y < hi) atomicAdd(&deg[d4.y], 1);
      if (d4.z >= lo && d4.z < hi) atomicAdd(&deg[d4.z], 1);
      if (d4.w >= lo && d4.w < hi) atomicAdd(&deg[d4.w], 1);
    } else {
      for (int j = 0; j < 4; ++j) {
        int ee = e + j;
        if (ee < E) {
          int d = dst[ee];
          if (d >= lo && d < hi) atomicAdd(&deg[d], 1);
        }
      }
    }
  }
}

__device__ __forceinline__ void fill_chunk(int c, int lo, int hi,
                                           const int* __restrict__ src,
                                           const int* __restrict__ dst,
                                           int* __restrict__ fillc,
                                           int* __restrict__ csr_src, int E) {
  const int base = c * ECHUNK + threadIdx.x * 4;
#pragma unroll
  for (int h = 0; h < 2; ++h) {
    int e = base + h * 1024;
    if (e + 3 < E) {
      iv4 d4 = __builtin_nontemporal_load(reinterpret_cast<const iv4*>(&dst[e]));
      iv4 s4 = __builtin_nontemporal_load(reinterpret_cast<const iv4*>(&src[e]));
      if (d4.x >= lo && d4.x < hi) csr_src[atomicAdd(&fillc[d4.x], 1)] = s4.x;
      if (d4.y >= lo && d4.y < hi) csr_src[atomicAdd(&fillc[d4.y], 1)] = s4.y;
      if (d4.z >= lo && d4.z < hi) csr_src[atomicAdd(&fillc[d4.z], 1)] = s4.z;
      if (d4.w >= lo && d4.w < hi) csr_src[atomicAdd(&fillc[d4.w], 1)] = s4.w;
    } else {
      for (int j = 0; j < 4; ++j) {
        int ee = e + j;
        if (ee < E) {
          int d = dst[ee];
          if (d >= lo && d < hi) csr_src[atomicAdd(&fillc[d], 1)] = src[ee];
        }
      }
    }
  }
}

// Hh[idx*8..+7] *= dinv[row]; nt load/store (streaming; keep L2 for fill)
__device__ __forceinline__ void scale_body(int bid, __half* __restrict__ Hh,
                                           const float* __restrict__ dinv, int N) {
  int idx = bid * 256 + threadIdx.x;
  if (idx >= N * 8) return;
  float s = dinv[idx >> 3];
  sv8 raw = __builtin_nontemporal_load(reinterpret_cast<sv8*>(&Hh[(size_t)idx * 8]));
  half8 v = *reinterpret_cast<half8*>(&raw);
  float2 f;
  f = __half22float2(v.lo.a); v.lo.a = __floats2half2_rn(f.x * s, f.y * s);
  f = __half22float2(v.lo.b); v.lo.b = __floats2half2_rn(f.x * s, f.y * s);
  f = __half22float2(v.hi.a); v.hi.a = __floats2half2_rn(f.x * s, f.y * s);
  f = __half22float2(v.hi.b); v.hi.b = __floats2half2_rn(f.x * s, f.y * s);
  __builtin_nontemporal_store(*reinterpret_cast<sv8*>(&v),
                              reinterpret_cast<sv8*>(&Hh[(size_t)idx * 8]));
}

// ---------------- scans ----------------

__global__ __launch_bounds__(SCAN_T) void k_scan1(const int* __restrict__ deg,
                                                  int* __restrict__ pre,
                                                  int* __restrict__ bsum, int N) {
  __shared__ int ls[SCAN_T];
  int t = threadIdx.x;
  int base = blockIdx.x * SCAN_B + t * SCAN_E;
  int v[SCAN_E];
  int s = 0;
#pragma unroll
  for (int j = 0; j < SCAN_E; ++j) {
    int idx = base + j;
    v[j] = (idx < N) ? deg[idx] : 0;
    s += v[j];
  }
  ls[t] = s;
  __syncthreads();
  for (int off = 1; off < SCAN_T; off <<= 1) {
    int x = 0;
    if (t >= off) x = ls[t - off];
    __syncthreads();
    ls[t] += x;
    __syncthreads();
  }
  if (t == SCAN_T - 1) bsum[blockIdx.x] = ls[t];
  int run = (t > 0) ? ls[t - 1] : 0;
#pragma unroll
  for (int j = 0; j < SCAN_E; ++j) {
    int idx = base + j;
    if (idx < N) pre[idx] = run;
    run += v[j];
  }
}

__global__ __launch_bounds__(SCAN_T) void k_scan2(int* __restrict__ bsum, int nb) {
  __shared__ int ls[SCAN_T];
  int t = threadIdx.x;
  ls[t] = (t < nb) ? bsum[t] : 0;
  __syncthreads();
  for (int off = 1; off < SCAN_T; off <<= 1) {
    int x = 0;
    if (t >= off) x = ls[t - off];
    __syncthreads();
    ls[t] += x;
    __syncthreads();
  }
  if (t < nb) bsum[t] = (t > 0) ? ls[t - 1] : 0;
}

__global__ __launch_bounds__(256) void k_scan3(int* __restrict__ rowptr,
                                               int* __restrict__ fillc,
                                               const int* __restrict__ bsum,
                                               const int* __restrict__ deg,
                                               float* __restrict__ dinv,
                                               int N, int E) {
  int i = blockIdx.x * 256 + threadIdx.x;
  if (i < N) {
    int r = rowptr[i] + bsum[i / SCAN_B];
    rowptr[i] = r;
    fillc[i] = r;
    int d = deg[i];
    dinv[i] = (d > 0) ? rsqrtf((float)d) : 0.f;
  }
  if (i == 0) rowptr[N] = E;
}

// ---------------- GEMM body ----------------
template <int K, int F, typename Tin, bool SCALE>
__device__ __forceinline__ void gemm_body(int bid, const Tin* __restrict__ X,
                                          const float* __restrict__ W,
                                          const float* __restrict__ dinv,
                                          __half* __restrict__ Hh, int N) {
  constexpr int CG = F / 4;
  constexpr int RG = 256 / CG;
  constexpr int ROWS = RG * 4;
  constexpr int KC = (K > 64) ? 64 : K;
  constexpr int NC = K / KC;
  constexpr int XP = KC + 4;
  __shared__ float Wl[KC * F];
  __shared__ float Xl[ROWS * XP];

  const int t = threadIdx.x;
  const int row0 = bid * ROWS;
  const int cg = t % CG;
  const int rg = t / CG;
  float4 a0 = make_float4(0.f, 0.f, 0.f, 0.f);
  float4 a1 = make_float4(0.f, 0.f, 0.f, 0.f);
  float4 a2 = make_float4(0.f, 0.f, 0.f, 0.f);
  float4 a3 = make_float4(0.f, 0.f, 0.f, 0.f);

  for (int c = 0; c < NC; ++c) {
    __syncthreads();
    for (int i = t; i < KC * F / 4; i += 256)
      reinterpret_cast<float4*>(Wl)[i] =
          reinterpret_cast<const float4*>(W + c * KC * F)[i];
    for (int i = t; i < ROWS * KC / 4; i += 256) {
      int r = (i * 4) / KC, col = (i * 4) % KC;
      int row = row0 + r;
      float4 v = make_float4(0.f, 0.f, 0.f, 0.f);
      if (row < N) {
        if constexpr (std::is_same<Tin, float>::value) {
          v = *reinterpret_cast<const float4*>(&X[(size_t)row * K + c * KC + col]);
        } else {
          half4 hv = *reinterpret_cast<const half4*>(&X[(size_t)row * K + c * KC + col]);
          float2 lo = __half22float2(hv.a), hi = __half22float2(hv.b);
          v = make_float4(lo.x, lo.y, hi.x, hi.y);
        }
      }
      *reinterpret_cast<float4*>(&Xl[r * XP + col]) = v;
    }
    __syncthreads();
    if (rg < RG) {
      const float* xr = &Xl[rg * 4 * XP];
      const float* wb = &Wl[cg * 4];
#pragma unroll 2
      for (int k = 0; k < KC; k += 4) {
        float4 w0 = *reinterpret_cast<const float4*>(&wb[(k + 0) * F]);
        float4 w1 = *reinterpret_cast<const float4*>(&wb[(k + 1) * F]);
        float4 w2 = *reinterpret_cast<const float4*>(&wb[(k + 2) * F]);
        float4 w3 = *reinterpret_cast<const float4*>(&wb[(k + 3) * F]);
        float4 x0 = *reinterpret_cast<const float4*>(&xr[0 * XP + k]);
        float4 x1 = *reinterpret_cast<const float4*>(&xr[1 * XP + k]);
        float4 x2 = *reinterpret_cast<const float4*>(&xr[2 * XP + k]);
        float4 x3 = *reinterpret_cast<const float4*>(&xr[3 * XP + k]);
        a0.x = fmaf(x0.x, w0.x, a0.x); a0.y = fmaf(x0.x, w0.y, a0.y);
        a0.z = fmaf(x0.x, w0.z, a0.z); a0.w = fmaf(x0.x, w0.w, a0.w);
        a1.x = fmaf(x1.x, w0.x, a1.x); a1.y = fmaf(x1.x, w0.y, a1.y);
        a1.z = fmaf(x1.x, w0.z, a1.z); a1.w = fmaf(x1.x, w0.w, a1.w);
        a2.x = fmaf(x2.x, w0.x, a2.x); a2.y = fmaf(x2.x, w0.y, a2.y);
        a2.z = fmaf(x2.x, w0.z, a2.z); a2.w = fmaf(x2.x, w0.w, a2.w);
        a3.x = fmaf(x3.x, w0.x, a3.x); a3.y = fmaf(x3.x, w0.y, a3.y);
        a3.z = fmaf(x3.x, w0.z, a3.z); a3.w = fmaf(x3.x, w0.w, a3.w);

        a0.x = fmaf(x0.y, w1.x, a0.x); a0.y = fmaf(x0.y, w1.y, a0.y);
        a0.z = fmaf(x0.y, w1.z, a0.z); a0.w = fmaf(x0.y, w1.w, a0.w);
        a1.x = fmaf(x1.y, w1.x, a1.x); a1.y = fmaf(x1.y, w1.y, a1.y);
        a1.z = fmaf(x1.y, w1.z, a1.z); a1.w = fmaf(x1.y, w1.w, a1.w);
        a2.x = fmaf(x2.y, w1.x, a2.x); a2.y = fmaf(x2.y, w1.y, a2.y);
        a2.z = fmaf(x2.y, w1.z, a2.z); a2.w = fmaf(x2.y, w1.w, a2.w);
        a3.x = fmaf(x3.y, w1.x, a3.x); a3.y = fmaf(x3.y, w1.y, a3.y);
        a3.z = fmaf(x3.y, w1.z, a3.z); a3.w = fmaf(x3.y, w1.w, a3.w);

        a0.x = fmaf(x0.z, w2.x, a0.x); a0.y = fmaf(x0.z, w2.y, a0.y);
        a0.z = fmaf(x0.z, w2.z, a0.z); a0.w = fmaf(x0.z, w2.w, a0.w);
        a1.x = fmaf(x1.z, w2.x, a1.x); a1.y = fmaf(x1.z, w2.y, a1.y);
        a1.z = fmaf(x1.z, w2.z, a1.z); a1.w = fmaf(x1.z, w2.w, a1.w);
        a2.x = fmaf(x2.z, w2.x, a2.x); a2.y = fmaf(x2.z, w2.y, a2.y);
        a2.z = fmaf(x2.z, w2.z, a2.z); a2.w = fmaf(x2.z, w2.w, a2.w);
        a3.x = fmaf(x3.z, w2.x, a3.x); a3.y = fmaf(x3.z, w2.y, a3.y);
        a3.z = fmaf(x3.z, w2.z, a3.z); a3.w = fmaf(x3.z, w2.w, a3.w);

        a0.x = fmaf(x0.w, w3.x, a0.x); a0.y = fmaf(x0.w, w3.y, a0.y);
        a0.z = fmaf(x0.w, w3.z, a0.z); a0.w = fmaf(x0.w, w3.w, a0.w);
        a1.x = fmaf(x1.w, w3.x, a1.x); a1.y = fmaf(x1.w, w3.y, a1.y);
        a1.z = fmaf(x1.w, w3.z, a1.z); a1.w = fmaf(x1.w, w3.w, a1.w);
        a2.x = fmaf(x2.w, w3.x, a2.x); a2.y = fmaf(x2.w, w3.y, a2.y);
        a2.z = fmaf(x2.w, w3.z, a2.z); a2.w = fmaf(x2.w, w3.w, a2.w);
        a3.x = fmaf(x3.w, w3.x, a3.x); a3.y = fmaf(x3.w, w3.y, a3.y);
        a3.z = fmaf(x3.w, w3.z, a3.z); a3.w = fmaf(x3.w, w3.w, a3.w);
      }
    }
  }

  if (rg < RG) {
    const int col = cg * 4;
    const int row = row0 + rg * 4;
#pragma unroll
    for (int r = 0; r < 4; ++r) {
      if (row + r < N) {
        float4 v = (r == 0) ? a0 : (r == 1) ? a1 : (r == 2) ? a2 : a3;
        float s = 1.f;
        if constexpr (SCALE) s = dinv[row + r];
        half4 o;
        o.a = __floats2half2_rn(v.x * s, v.y * s);
        o.b = __floats2half2_rn(v.z * s, v.w * s);
        *reinterpret_cast<half4*>(&Hh[(size_t)(row + r) * F + col]) = o;
      }
    }
  }
}

template <int K, int F>
__global__ __launch_bounds__(256) void k_gemm_h(const __half* __restrict__ X,
                                                const float* __restrict__ W,
                                                const float* __restrict__ dinv,
                                                __half* __restrict__ Hh, int N) {
  gemm_body<K, F, __half, true>(blockIdx.x, X, W, dinv, Hh, N);
}

// fused1: slots of 7 = 3 gemm blocks + 4 count workers (static partitions).
__global__ __launch_bounds__(256) void k_fused1(const float* __restrict__ X,
                                                const float* __restrict__ W,
                                                __half* __restrict__ Hh, int N,
                                                int gemmBlocks,
                                                const int* __restrict__ dst,
                                                int* __restrict__ deg,
                                                int E, int PS, int nchunks) {
  const int bid = (int)blockIdx.x;
  const int slot = bid / 7, r = bid % 7;
  if (r < 3) {
    int g = slot * 3 + r;
    if (g < gemmBlocks) gemm_body<128, 64, float, false>(g, X, W, nullptr, Hh, N);
    return;
  }
  int widx = slot * 4 + (r - 3);
  if (widx >= NWORK) return;
  const int p = widx & 7;
  const int lo = p * PS, hi = lo + PS;
  for (int c = widx >> 3; c < nchunks; c += WSTRIDE)
    count_chunk(c, lo, hi, dst, deg, E);
}

// fused2: slots of 5 = 3 scale blocks + 2 fill workers (static partitions).
__global__ __launch_bounds__(256) void k_fused2(const int* __restrict__ src,
                                                const int* __restrict__ dst,
                                                int* __restrict__ fillc,
                                                int* __restrict__ csr_src,
                                                int E, int PS, int nchunks,
                                                __half* __restrict__ Hh,
                                                const float* __restrict__ dinv,
                                                int N, int scaleBlocks) {
  const int bid = (int)blockIdx.x;
  const int slot = bid / 5, r = bid % 5;
  if (r < 3) {
    int sb = slot * 3 + r;
    if (sb < scaleBlocks) scale_body(sb, Hh, dinv, N);
    return;
  }
  int widx = slot * 2 + (r - 3);
  if (widx >= NWORK) return;
  const int p = widx & 7;
  const int lo = p * PS, hi = lo + PS;
  for (int c = widx >> 3; c < nchunks; c += WSTRIDE)
    fill_chunk(c, lo, hi, src, dst, fillc, csr_src, E);
}

// ---------------- aggregation ----------------
template <int F, bool BNR, typename Tout>
__global__ __launch_bounds__(256) void k_agg(const __half* __restrict__ H,
                                             Tout* __restrict__ G,
                                             const int* __restrict__ rowptr,
                                             const int* __restrict__ csr_src,
                                             const float* __restrict__ dinv,
                                             const float* __restrict__ bias,
                                             const float* __restrict__ gam,
                                             const float* __restrict__ bet,
                                             const float* __restrict__ mu,
                                             const float* __restrict__ var, int N) {
  constexpr int LPG = F / 4;
  int node = (blockIdx.x * 256 + threadIdx.x) >> 6;
  int lane = threadIdx.x & 63;
  if (node >= N) return;
  int g = lane >> 4, gl = lane & 15;
  bool active = gl < LPG;
  int p0 = rowptr[node], p1 = rowptr[node + 1];
  float4 a0 = make_float4(0.f, 0.f, 0.f, 0.f);
  float4 a1 = make_float4(0.f, 0.f, 0.f, 0.f);
  int p = p0 + g;
  for (; p + 4 < p1; p += 8) {
    int s0 = csr_src[p];
    int s1 = csr_src[p + 4];
    if (active) {
      half4 h0 = *reinterpret_cast<const half4*>(&H[(size_t)s0 * F + gl * 4]);
      half4 h1 = *reinterpret_cast<const half4*>(&H[(size_t)s1 * F + gl * 4]);
      float2 l0 = __half22float2(h0.a), u0 = __half22float2(h0.b);
      float2 l1 = __half22float2(h1.a), u1 = __half22float2(h1.b);
      a0.x += l0.x; a0.y += l0.y; a0.z += u0.x; a0.w += u0.y;
      a1.x += l1.x; a1.y += l1.y; a1.z += u1.x; a1.w += u1.y;
    }
  }
  if (p < p1) {
    int s0 = csr_src[p];
    if (active) {
      half4 h0 = *reinterpret_cast<const half4*>(&H[(size_t)s0 * F + gl * 4]);
      float2 l0 = __half22float2(h0.a), u0 = __half22float2(h0.b);
      a0.x += l0.x; a0.y += l0.y; a0.z += u0.x; a0.w += u0.y;
    }
  }
  a0.x += a1.x; a0.y += a1.y; a0.z += a1.z; a0.w += a1.w;
#pragma unroll
  for (int off = 16; off <= 32; off <<= 1) {
    a0.x += __shfl_xor(a0.x, off);
    a0.y += __shfl_xor(a0.y, off);
    a0.z += __shfl_xor(a0.z, off);
    a0.w += __shfl_xor(a0.w, off);
  }
  if (g == 0 && active) {
    int f = gl * 4;
    float di = dinv[node];
    float4 y;
    y.x = fmaf(di, a0.x, bias[f + 0]);
    y.y = fmaf(di, a0.y, bias[f + 1]);
    y.z = fmaf(di, a0.z, bias[f + 2]);
    y.w = fmaf(di, a0.w, bias[f + 3]);
    if (BNR) {
      y.x = fmaxf((y.x - mu[f + 0]) * rsqrtf(var[f + 0] + 1e-5f) * gam[f + 0] + bet[f + 0], 0.f);
      y.y = fmaxf((y.y - mu[f + 1]) * rsqrtf(var[f + 1] + 1e-5f) * gam[f + 1] + bet[f + 1], 0.f);
      y.z = fmaxf((y.z - mu[f + 2]) * rsqrtf(var[f + 2] + 1e-5f) * gam[f + 2] + bet[f + 2], 0.f);
      y.w = fmaxf((y.w - mu[f + 3]) * rsqrtf(var[f + 3] + 1e-5f) * gam[f + 3] + bet[f + 3], 0.f);
    }
    if constexpr (std::is_same<Tout, __half>::value) {
      half4 o;
      o.a = __floats2half2_rn(y.x, y.y);
      o.b = __floats2half2_rn(y.z, y.w);
      *reinterpret_cast<half4*>(&G[(size_t)node * F + f]) = o;
    } else {
      *reinterpret_cast<float4*>(&G[(size_t)node * F + f]) = y;
    }
  }
}

extern "C" void kernel_launch(void* const* d_in, const int* in_sizes, int n_in,
                              void* d_out, int out_size, void* d_ws, size_t ws_size,
                              hipStream_t stream) {
  const float* x  = (const float*)d_in[0];
  const int*   ei = (const int*)d_in[1];
  const float* W1 = (const float*)d_in[2];
  const float* b1 = (const float*)d_in[3];
  const float* W2 = (const float*)d_in[4];
  const float* b2 = (const float*)d_in[5];
  const float* W3 = (const float*)d_in[6];
  const float* b3 = (const float*)d_in[7];
  const float* g1 = (const float*)d_in[8];
  const float* be1 = (const float*)d_in[9];
  const float* m1 = (const float*)d_in[10];
  const float* v1 = (const float*)d_in[11];
  const float* g2 = (const float*)d_in[12];
  const float* be2 = (const float*)d_in[13];
  const float* m2 = (const float*)d_in[14];
  const float* v2 = (const float*)d_in[15];

  const int N = in_sizes[0] / 128;  // 100000
  const int E = in_sizes[1] / 2;    // 1000000
  const int* src = ei;
  const int* dst = ei + E;

  char* w = (char*)d_ws;
  size_t off = 0;
  auto take = [&](size_t bytes) -> void* {
    void* p = w + off;
    off += (bytes + 511) & ~size_t(511);
    return p;
  };
  int*    deg     = (int*)take((size_t)N * 4);
  size_t  zeroB   = off;                     // deg zeroed
  int*    fillc   = (int*)take((size_t)N * 4);
  int*    rowptr  = (int*)take(((size_t)N + 1) * 4);
  float*  dinv    = (float*)take((size_t)N * 4);
  int*    bsum    = (int*)take((size_t)SCAN_T * 4);
  int*    csr_src = (int*)take((size_t)E * 4);
  __half* Hh      = (__half*)take((size_t)N * 64 * 2);
  __half* Gh      = (__half*)take((size_t)N * 64 * 2);
  if (off > ws_size) return;

  const int nb = (N + SCAN_B - 1) / SCAN_B;           // 49
  const int PS = (N + NPART - 1) / NPART;             // 12500
  const int nchunks = (E + ECHUNK - 1) / ECHUNK;      // 489
  const int gemm1Blocks = (N + 63) / 64;              // 1563
  const int scaleBlocks = (N * 8 + 255) / 256;        // 3125
  // fused1: slots of 7 (3 gemm + 4 workers); need gemm coverage and >=NWORK workers
  const int f1Slots = ((gemm1Blocks + 2) / 3) > (NWORK / 4) ? ((gemm1Blocks + 2) / 3)
                                                            : (NWORK / 4);
  const int f1Grid = f1Slots * 7;                     // 3647
  // fused2: slots of 5 (3 scale + 2 workers)
  const int f2Slots = ((scaleBlocks + 2) / 3) > (NWORK / 2) ? ((scaleBlocks + 2) / 3)
                                                            : (NWORK / 2);
  const int f2Grid = f2Slots * 5;                     // 5210

  hipMemsetAsync(d_ws, 0, zeroB, stream);
  k_fused1<<<f1Grid, 256, 0, stream>>>(x, W1, Hh, N, gemm1Blocks,
                                       dst, deg, E, PS, nchunks);
  k_scan1<<<nb, SCAN_T, 0, stream>>>(deg, rowptr, bsum, N);
  k_scan2<<<1, SCAN_T, 0, stream>>>(bsum, nb);
  k_scan3<<<(N + 255) / 256, 256, 0, stream>>>(rowptr, fillc, bsum, deg, dinv, N, E);
  k_fused2<<<f2Grid, 256, 0, stream>>>(src, dst, fillc, csr_src, E, PS, nchunks,
                                       Hh, dinv, N, scaleBlocks);

  // layer 1 aggregation -> Gh (fp16)
  k_agg<64, true, __half><<<(N + 3) / 4, 256, 0, stream>>>(
      Hh, Gh, rowptr, csr_src, dinv, b1, g1, be1, m1, v1, N);
  // layer 2
  k_gemm_h<64, 64><<<(N + 63) / 64, 256, 0, stream>>>(Gh, W2, dinv, Hh, N);
  k_agg<64, true, __half><<<(N + 3) / 4, 256, 0, stream>>>(
      Hh, Gh, rowptr, csr_src, dinv, b2, g2, be2, m2, v2, N);
  // output layer
  k_gemm_h<64, 40><<<(N + 99) / 100, 256, 0, stream>>>(Gh, W3, dinv, Hh, N);
  k_agg<40, false, float><<<(N + 3) / 4, 256, 0, stream>>>(
      Hh, (float*)d_out, rowptr, csr_src, dinv, b3, nullptr, nullptr, nullptr,
      nullptr, N);
}